// Round 5
// baseline (623.375 us; speedup 1.0000x reference)
//
#include <hip/hip_runtime.h>
#include <math.h>

#define N_ATOMS 50000
#define M_NBR   12
#define A_FEA   64
#define B_FEA   41
#define KF      169      // 2*A + B
#define KP      192      // padded K (6 chunks of 32)
#define LDA     200      // LDS row stride in bf16 (400 B -> free 2-way banking)
#define OC      128      // 2*A
#define NROW    600000   // N_ATOMS * M_NBR
#define TILE_R  64
#define NTILES  9375     // NROW / TILE_R
#define BN_EPS  1e-5f
#define L2E     1.44269504088896340736f
#define LN2     0.693147180559945309417f

// d_ws layout
#define WS_SUM1   0
#define WS_SUMSQ1 128
#define WS_SUM2   256
#define WS_SUMSQ2 320
#define WS_NFLOAT 384
#define WS_GATED_OFF 2048ull                       // byte offset of gated buffer
#define GATED_BYTES  ((size_t)NTILES * 256 * 64)   // 153.6 MB of bf16

typedef __attribute__((ext_vector_type(8))) short s16x8;
typedef __attribute__((ext_vector_type(4))) float f32x4;

__device__ __forceinline__ float fsigmoid(float x) {
    float e = __builtin_amdgcn_exp2f(-x * L2E);
    return __builtin_amdgcn_rcpf(1.f + e);
}
__device__ __forceinline__ float fsoftplus(float x) {
    float e = __builtin_amdgcn_exp2f(-fabsf(x) * L2E);
    return fmaxf(x, 0.f) + __builtin_amdgcn_logf(1.f + e) * LN2;
}
__device__ __forceinline__ unsigned short f2bf(float f) {
    unsigned int u = __float_as_uint(f);
    u += 0x7FFFu + ((u >> 16) & 1u);     // RNE
    return (unsigned short)(u >> 16);
}
__device__ __forceinline__ unsigned int pack2bf(float lo, float hi) {
    return (unsigned int)f2bf(lo) | ((unsigned int)f2bf(hi) << 16);
}
__device__ __forceinline__ float bf_lo(unsigned int u) { return __uint_as_float(u << 16); }
__device__ __forceinline__ float bf_hi(unsigned int u) { return __uint_as_float(u & 0xFFFF0000u); }

__global__ void k_zero(float* __restrict__ dout, float* __restrict__ stats) {
    int i = blockIdx.x * blockDim.x + threadIdx.x;
    int stride = gridDim.x * blockDim.x;
    for (int j = i; j < N_ATOMS * A_FEA; j += stride) dout[j] = 0.f;
    if (i < WS_NFLOAT) stats[i] = 0.f;
}

__device__ __forceinline__ void zero_At_pad(unsigned short* __restrict__ At, int tid) {
    for (unsigned i = tid; i < TILE_R * (KP - KF); i += 256) {
        unsigned r = i / (unsigned)(KP - KF);
        unsigned j = KF + (i - r * (KP - KF));
        At[r * LDA + j] = 0;
    }
}

// Wide-load staging: batch1 (self float4 x4, idx x4, bond float4 x3) issued
// together, written, then batch2 (gathers float4 x4). ~13 wide loads/thread.
__device__ __forceinline__ void stage_tile(unsigned short* __restrict__ At,
                                           const float* __restrict__ atom,
                                           const float* __restrict__ nbr,
                                           const int* __restrict__ idx,
                                           int rb, int tid) {
    const int r16 = tid >> 4;         // rows r16 + 16*it
    const int k4  = (tid & 15) * 4;   // float4 k-offset
    float4 selfv[4], bondv[3];
    int nbi[4];
#pragma unroll
    for (int it = 0; it < 4; ++it) {
        int row = rb + r16 + it * 16;
        selfv[it] = *(const float4*)(atom + ((unsigned)row / 12u) * A_FEA + k4);
    }
#pragma unroll
    for (int it = 0; it < 4; ++it) nbi[it] = idx[rb + r16 + it * 16];
    const float* bb = nbr + (size_t)rb * B_FEA;   // 2624 floats = 656 float4
#pragma unroll
    for (int it = 0; it < 3; ++it) {
        int i4 = tid + it * 256;
        if (i4 < 656) bondv[it] = *(const float4*)(bb + i4 * 4);
    }
#pragma unroll
    for (int it = 0; it < 4; ++it) {
        int r = r16 + it * 16;
        uint2 u;
        u.x = pack2bf(selfv[it].x, selfv[it].y);
        u.y = pack2bf(selfv[it].z, selfv[it].w);
        *(uint2*)&At[r * LDA + k4] = u;
    }
#pragma unroll
    for (int it = 0; it < 3; ++it) {
        int i4 = tid + it * 256;
        if (i4 < 656) {
            const float bv[4] = {bondv[it].x, bondv[it].y, bondv[it].z, bondv[it].w};
#pragma unroll
            for (int e = 0; e < 4; ++e) {
                int le = i4 * 4 + e;
                unsigned r = (unsigned)le / 41u;
                unsigned j = (unsigned)le - r * 41u;
                At[r * LDA + 2 * A_FEA + j] = f2bf(bv[e]);   // handles row-crossing
            }
        }
    }
    float4 gat[4];
#pragma unroll
    for (int it = 0; it < 4; ++it)
        gat[it] = *(const float4*)(atom + (unsigned)nbi[it] * A_FEA + k4);
#pragma unroll
    for (int it = 0; it < 4; ++it) {
        int r = r16 + it * 16;
        uint2 u;
        u.x = pack2bf(gat[it].x, gat[it].y);
        u.y = pack2bf(gat[it].z, gat[it].w);
        *(uint2*)&At[r * LDA + A_FEA + k4] = u;
    }
}

// Per-wave W fragments (B operand) from global into registers, once.
__device__ __forceinline__ void load_wfrag(s16x8 bfr[4][6], const float* __restrict__ W,
                                           const int ct[4], int col, int q8) {
#pragma unroll
    for (int t = 0; t < 4; ++t) {
        const float* wr = W + (ct[t] * 16 + col) * KF;
#pragma unroll
        for (int kc = 0; kc < 6; ++kc) {
            const int kb = kc * 32 + q8;
            s16x8 f;
#pragma unroll
            for (int j = 0; j < 8; ++j) {
                int k = kb + j;
                float v = (k < KF) ? wr[k] : 0.f;
                f[j] = (short)f2bf(v);
            }
            bfr[t][kc] = f;
        }
    }
}

__device__ __forceinline__ void gemm_core(const unsigned short* __restrict__ At,
                                          const s16x8 bfr[4][6],
                                          int r0, int col, int q8, f32x4 acc[2][4]) {
#pragma unroll
    for (int rt = 0; rt < 2; ++rt)
#pragma unroll
        for (int t = 0; t < 4; ++t) acc[rt][t] = (f32x4){0.f, 0.f, 0.f, 0.f};
#pragma unroll
    for (int kc = 0; kc < 6; ++kc) {
        const int k0 = kc * 32;
        const s16x8 a0 = *(const s16x8*)&At[(r0 + col) * LDA + k0 + q8];
        const s16x8 a1 = *(const s16x8*)&At[(r0 + 16 + col) * LDA + k0 + q8];
#pragma unroll
        for (int t = 0; t < 4; ++t) {
            acc[0][t] = __builtin_amdgcn_mfma_f32_16x16x32_bf16(a0, bfr[t][kc], acc[0][t], 0, 0, 0);
            acc[1][t] = __builtin_amdgcn_mfma_f32_16x16x32_bf16(a1, bfr[t][kc], acc[1][t], 0, 0, 0);
        }
    }
}

// ---- fused pass: GEMM once; BN1 stats + store raw gated tile as bf16 to ws.
// Storage layout (uint2 units): gated[tile*2048 + v*256 + tid], v = rt*4+t.
// Each store instruction is lane-consecutive -> fully coalesced.
template <bool STORE>
__global__ __launch_bounds__(256, 4)
void k_gemm_stats_t(const float* __restrict__ atom, const float* __restrict__ nbr,
                    const int* __restrict__ idx, const float* __restrict__ W,
                    float* __restrict__ stats, uint2* __restrict__ gated) {
    __shared__ __align__(16) unsigned short At[TILE_R * LDA];  // 25600 B
    const int tid = threadIdx.x;
    zero_At_pad(At, tid);

    const int lane = tid & 63;
    const int w    = tid >> 6;
    const int col  = lane & 15;
    const int q8   = (lane >> 4) * 8;
    const int r0   = (w & 1) * 32;
    const int g    = w >> 1;
    const int ct[4] = {2 * g, 2 * g + 1, 2 * g + 4, 2 * g + 5};

    s16x8 bfr[4][6];
    load_wfrag(bfr, W, ct, col, q8);

    float s[4] = {0.f, 0.f, 0.f, 0.f}, q[4] = {0.f, 0.f, 0.f, 0.f};

    const int step = gridDim.x * TILE_R;
    for (int rb = blockIdx.x * TILE_R; rb < NROW; rb += step) {
        __syncthreads();
        stage_tile(At, atom, nbr, idx, rb, tid);
        __syncthreads();

        f32x4 acc[2][4];
        gemm_core(At, bfr, r0, col, q8, acc);

#pragma unroll
        for (int rt = 0; rt < 2; ++rt)
#pragma unroll
            for (int t = 0; t < 4; ++t) {
#pragma unroll
                for (int e = 0; e < 4; ++e) {
                    float v = acc[rt][t][e];
                    s[t] += v; q[t] = fmaf(v, v, q[t]);
                }
                if (STORE) {
                    uint2 u;
                    u.x = pack2bf(acc[rt][t][0], acc[rt][t][1]);
                    u.y = pack2bf(acc[rt][t][2], acc[rt][t][3]);
                    gated[(size_t)(rb >> 6) * 2048 + (rt * 4 + t) * 256 + tid] = u;
                }
            }
    }
#pragma unroll
    for (int t = 0; t < 4; ++t) {
        float sv = s[t], qv = q[t];
        sv += __shfl_xor(sv, 16); sv += __shfl_xor(sv, 32);
        qv += __shfl_xor(qv, 16); qv += __shfl_xor(qv, 32);
        if (lane < 16) {
            int c = ct[t] * 16 + col;
            atomicAdd(&stats[WS_SUM1 + c], sv);
            atomicAdd(&stats[WS_SUMSQ1 + c], qv);
        }
    }
}

// ---- apply pass (fused path): stream gated bf16, BN1 + sig*softplus + m-sum.
__global__ __launch_bounds__(256, 8)
void k_apply(const uint2* __restrict__ gated,
             const float* __restrict__ g1, const float* __restrict__ b1,
             const float* __restrict__ stats, float* __restrict__ dout) {
    __shared__ float S[7 * 64];
    const int tid = threadIdx.x;
    for (int i = tid; i < 7 * 64; i += 256) S[i] = 0.f;

    const int lane = tid & 63;
    const int w    = tid >> 6;
    const int col  = lane & 15;
    const int r0   = (w & 1) * 32;
    const int g    = w >> 1;
    const int ct[4] = {2 * g, 2 * g + 1, 2 * g + 4, 2 * g + 5};

    const float invn = 1.f / (float)NROW;
    float sc[4], sh[4];
#pragma unroll
    for (int t = 0; t < 4; ++t) {
        int c = ct[t] * 16 + col;
        float mean = stats[WS_SUM1 + c] * invn;
        float var  = stats[WS_SUMSQ1 + c] * invn - mean * mean;
        sc[t] = g1[c] * rsqrtf(var + BN_EPS);
        sh[t] = b1[c] - mean * sc[t];
    }

    for (int tile = blockIdx.x; tile < NTILES; tile += gridDim.x) {
        __syncthreads();                  // S zeroed / previous flush complete
        uint2 u[8];
#pragma unroll
        for (int v = 0; v < 8; ++v)
            u[v] = gated[(size_t)tile * 2048 + v * 256 + tid];

        const int rb  = tile * TILE_R;
        const int a0i = rb / M_NBR;
#pragma unroll
        for (int p = 0; p < 2; ++p) {
            const int c = ct[p] * 16 + col;
#pragma unroll
            for (int rt = 0; rt < 2; ++rt) {
                const uint2 uf = u[rt * 4 + p];
                const uint2 uc = u[rt * 4 + p + 2];
                const float fv[4] = {bf_lo(uf.x), bf_hi(uf.x), bf_lo(uf.y), bf_hi(uf.y)};
                const float cv[4] = {bf_lo(uc.x), bf_hi(uc.x), bf_lo(uc.y), bf_hi(uc.y)};
#pragma unroll
                for (int e = 0; e < 4; ++e) {
                    float gF = fmaf(fv[e], sc[p],     sh[p]);
                    float gC = fmaf(cv[e], sc[p + 2], sh[p + 2]);
                    float v  = fsigmoid(gF) * fsoftplus(gC);
                    int row_local = r0 + rt * 16 + (lane >> 4) * 4 + e;
                    int al = (rb + row_local) / M_NBR - a0i;
                    atomicAdd(&S[al * 64 + c], v);
                }
            }
        }
        __syncthreads();
        const int amax = (rb + TILE_R - 1) / M_NBR - a0i;
        for (int i = tid; i < 7 * 64; i += 256) {
            float v = S[i];
            S[i] = 0.f;
            int a = i >> 6;
            if (a <= amax) atomicAdd(&dout[(a0i + a) * 64 + (i & 63)], v);
        }
    }
}

// ---- fallback two-pass main kernel (if ws too small): GEMM + epilogue.
__global__ __launch_bounds__(256, 4)
void k_gemm_main(const float* __restrict__ atom, const float* __restrict__ nbr,
                 const int* __restrict__ idx, const float* __restrict__ W,
                 const float* __restrict__ g1, const float* __restrict__ b1,
                 const float* __restrict__ stats, float* __restrict__ dout) {
    __shared__ __align__(16) unsigned short At[TILE_R * LDA];
    __shared__ float S[7 * 64];
    const int tid = threadIdx.x;
    zero_At_pad(At, tid);
    for (int i = tid; i < 7 * 64; i += 256) S[i] = 0.f;

    const int lane = tid & 63;
    const int w    = tid >> 6;
    const int col  = lane & 15;
    const int q8   = (lane >> 4) * 8;
    const int r0   = (w & 1) * 32;
    const int g    = w >> 1;
    const int ct[4] = {2 * g, 2 * g + 1, 2 * g + 4, 2 * g + 5};

    s16x8 bfr[4][6];
    load_wfrag(bfr, W, ct, col, q8);

    const float invn = 1.f / (float)NROW;
    float sc[4], sh[4];
#pragma unroll
    for (int t = 0; t < 4; ++t) {
        int c = ct[t] * 16 + col;
        float mean = stats[WS_SUM1 + c] * invn;
        float var  = stats[WS_SUMSQ1 + c] * invn - mean * mean;
        sc[t] = g1[c] * rsqrtf(var + BN_EPS);
        sh[t] = b1[c] - mean * sc[t];
    }

    const int step = gridDim.x * TILE_R;
    for (int rb = blockIdx.x * TILE_R; rb < NROW; rb += step) {
        __syncthreads();
        stage_tile(At, atom, nbr, idx, rb, tid);
        __syncthreads();

        f32x4 acc[2][4];
        gemm_core(At, bfr, r0, col, q8, acc);

        const int a0i = rb / M_NBR;
#pragma unroll
        for (int p = 0; p < 2; ++p) {
            const int c = ct[p] * 16 + col;
#pragma unroll
            for (int rt = 0; rt < 2; ++rt)
#pragma unroll
                for (int e = 0; e < 4; ++e) {
                    float gF = fmaf(acc[rt][p][e],     sc[p],     sh[p]);
                    float gC = fmaf(acc[rt][p + 2][e], sc[p + 2], sh[p + 2]);
                    float v  = fsigmoid(gF) * fsoftplus(gC);
                    int row_local = r0 + rt * 16 + (lane >> 4) * 4 + e;
                    int al = (rb + row_local) / M_NBR - a0i;
                    atomicAdd(&S[al * 64 + c], v);
                }
        }
        __syncthreads();
        const int amax = (rb + TILE_R - 1) / M_NBR - a0i;
        for (int i = tid; i < 7 * 64; i += 256) {
            float v = S[i];
            S[i] = 0.f;
            int a = i >> 6;
            if (a <= amax) atomicAdd(&dout[(a0i + a) * 64 + (i & 63)], v);
        }
    }
}

__global__ __launch_bounds__(256, 1)
void k_bn2_stats(const float* __restrict__ dout, float* __restrict__ stats) {
    int tid = threadIdx.x;
    int c = tid & 63;
    int g = tid >> 6;
    float s = 0.f, q = 0.f;
    for (int n = blockIdx.x * 4 + g; n < N_ATOMS; n += gridDim.x * 4) {
        float v = dout[n * 64 + c];
        s += v; q = fmaf(v, v, q);
    }
    __shared__ float red[4][64];
    red[g][c] = s;
    __syncthreads();
    if (g == 0)
        atomicAdd(&stats[WS_SUM2 + c], red[0][c] + red[1][c] + red[2][c] + red[3][c]);
    __syncthreads();
    red[g][c] = q;
    __syncthreads();
    if (g == 0)
        atomicAdd(&stats[WS_SUMSQ2 + c], red[0][c] + red[1][c] + red[2][c] + red[3][c]);
}

__global__ void k_final(const float* __restrict__ atom, const float* __restrict__ g2,
                        const float* __restrict__ b2, const float* __restrict__ stats,
                        float* __restrict__ dout) {
    int i0 = blockIdx.x * blockDim.x + threadIdx.x;
    int c = i0 & 63;
    const float invn = 1.f / (float)N_ATOMS;
    float mean = stats[WS_SUM2 + c] * invn;
    float var  = stats[WS_SUMSQ2 + c] * invn - mean * mean;
    float sc   = g2[c] * rsqrtf(var + BN_EPS);
    float sh   = b2[c] - mean * sc;
    int stride = gridDim.x * blockDim.x;
    for (int i = i0; i < N_ATOMS * A_FEA; i += stride) {
        float v = fmaf(dout[i], sc, sh) + atom[i];
        dout[i] = fsoftplus(v);
    }
}

extern "C" void kernel_launch(void* const* d_in, const int* in_sizes, int n_in,
                              void* d_out, int out_size, void* d_ws, size_t ws_size,
                              hipStream_t stream) {
    const float* atom = (const float*)d_in[0];
    const float* nbr  = (const float*)d_in[1];
    const int*   idx  = (const int*)d_in[2];
    const float* W    = (const float*)d_in[3];
    // d_in[4] (bias b) is mathematically absorbed by BN1 -> unused
    const float* g1   = (const float*)d_in[5];
    const float* b1   = (const float*)d_in[6];
    const float* g2   = (const float*)d_in[7];
    const float* b2   = (const float*)d_in[8];
    float* dout  = (float*)d_out;
    float* stats = (float*)d_ws;
    uint2* gated = (uint2*)((char*)d_ws + WS_GATED_OFF);

    const bool fused = ws_size >= (WS_GATED_OFF + GATED_BYTES);

    k_zero<<<512, 256, 0, stream>>>(dout, stats);
    if (fused) {
        k_gemm_stats_t<true><<<1024, 256, 0, stream>>>(atom, nbr, idx, W, stats, gated);
        k_apply<<<2048, 256, 0, stream>>>(gated, g1, b1, stats, dout);
    } else {
        k_gemm_stats_t<false><<<1024, 256, 0, stream>>>(atom, nbr, idx, W, stats, nullptr);
        k_gemm_main<<<1024, 256, 0, stream>>>(atom, nbr, idx, W, g1, b1, stats, dout);
    }
    k_bn2_stats<<<256, 256, 0, stream>>>(dout, stats);
    k_final<<<512, 256, 0, stream>>>(atom, g2, b2, stats, dout);
}

// Round 6
// 473.519 us; speedup vs baseline: 1.3165x; 1.3165x over previous
//
#include <hip/hip_runtime.h>
#include <math.h>

#define N_ATOMS 50000
#define M_NBR   12
#define A_FEA   64
#define B_FEA   41
#define KF      169      // 2*A + B
#define KP      192      // padded K (6 chunks of 32)
#define LDA     200      // LDS row stride in bf16 (400 B -> free 2-way banking)
#define OC      128      // 2*A
#define NROW    600000   // N_ATOMS * M_NBR
#define TILE_R  64
#define NTILES  9375     // NROW / TILE_R  (64-row tiles)
#define NT192   3125     // NROW / 192     (16-atom tiles)
#define S2S     68       // apply scratch stride (floats)
#define BN_EPS  1e-5f
#define L2E     1.44269504088896340736f
#define LN2     0.693147180559945309417f

// d_ws layout
#define WS_SUM1   0
#define WS_SUMSQ1 128
#define WS_SUM2   256
#define WS_SUMSQ2 320
#define WS_NFLOAT 384
#define WS_GATED_OFF 2048ull                       // byte offset of gated buffer
#define GATED_BYTES  ((size_t)NTILES * 256 * 64)   // 153.6 MB of bf16

typedef __attribute__((ext_vector_type(8))) short s16x8;
typedef __attribute__((ext_vector_type(4))) float f32x4;

__device__ __forceinline__ float fsigmoid(float x) {
    float e = __builtin_amdgcn_exp2f(-x * L2E);
    return __builtin_amdgcn_rcpf(1.f + e);
}
__device__ __forceinline__ float fsoftplus(float x) {
    float e = __builtin_amdgcn_exp2f(-fabsf(x) * L2E);
    return fmaxf(x, 0.f) + __builtin_amdgcn_logf(1.f + e) * LN2;
}
__device__ __forceinline__ unsigned short f2bf(float f) {
    unsigned int u = __float_as_uint(f);
    u += 0x7FFFu + ((u >> 16) & 1u);     // RNE
    return (unsigned short)(u >> 16);
}
__device__ __forceinline__ unsigned int pack2bf(float lo, float hi) {
    return (unsigned int)f2bf(lo) | ((unsigned int)f2bf(hi) << 16);
}
__device__ __forceinline__ float bf_lo(unsigned int u) { return __uint_as_float(u << 16); }
__device__ __forceinline__ float bf_hi(unsigned int u) { return __uint_as_float(u & 0xFFFF0000u); }

__global__ void k_zero_stats(float* __restrict__ stats) {
    int i = blockIdx.x * blockDim.x + threadIdx.x;
    if (i < WS_NFLOAT) stats[i] = 0.f;
}
__global__ void k_zero(float* __restrict__ dout, float* __restrict__ stats) {
    int i = blockIdx.x * blockDim.x + threadIdx.x;
    int stride = gridDim.x * blockDim.x;
    for (int j = i; j < N_ATOMS * A_FEA; j += stride) dout[j] = 0.f;
    if (i < WS_NFLOAT) stats[i] = 0.f;
}

__device__ __forceinline__ void zero_At_pad(unsigned short* __restrict__ At, int tid) {
    for (unsigned i = tid; i < TILE_R * (KP - KF); i += 256) {
        unsigned r = i / (unsigned)(KP - KF);
        unsigned j = KF + (i - r * (KP - KF));
        At[r * LDA + j] = 0;
    }
}

// Wide-load staging (batched latencies): self float4 x4 + idx x4 + bond float4 x3
// issued together, written; then gathers float4 x4.
__device__ __forceinline__ void stage_tile(unsigned short* __restrict__ At,
                                           const float* __restrict__ atom,
                                           const float* __restrict__ nbr,
                                           const int* __restrict__ idx,
                                           int rb, int tid) {
    const int r16 = tid >> 4;         // rows r16 + 16*it
    const int k4  = (tid & 15) * 4;   // float4 k-offset
    float4 selfv[4], bondv[3];
    int nbi[4];
#pragma unroll
    for (int it = 0; it < 4; ++it) {
        int row = rb + r16 + it * 16;
        selfv[it] = *(const float4*)(atom + ((unsigned)row / 12u) * A_FEA + k4);
    }
#pragma unroll
    for (int it = 0; it < 4; ++it) nbi[it] = idx[rb + r16 + it * 16];
    const float* bb = nbr + (size_t)rb * B_FEA;   // 2624 floats = 656 float4
#pragma unroll
    for (int it = 0; it < 3; ++it) {
        int i4 = tid + it * 256;
        if (i4 < 656) bondv[it] = *(const float4*)(bb + i4 * 4);
    }
#pragma unroll
    for (int it = 0; it < 4; ++it) {
        int r = r16 + it * 16;
        uint2 u;
        u.x = pack2bf(selfv[it].x, selfv[it].y);
        u.y = pack2bf(selfv[it].z, selfv[it].w);
        *(uint2*)&At[r * LDA + k4] = u;
    }
#pragma unroll
    for (int it = 0; it < 3; ++it) {
        int i4 = tid + it * 256;
        if (i4 < 656) {
            const float bv[4] = {bondv[it].x, bondv[it].y, bondv[it].z, bondv[it].w};
#pragma unroll
            for (int e = 0; e < 4; ++e) {
                int le = i4 * 4 + e;
                unsigned r = (unsigned)le / 41u;
                unsigned j = (unsigned)le - r * 41u;
                At[r * LDA + 2 * A_FEA + j] = f2bf(bv[e]);
            }
        }
    }
    float4 gat[4];
#pragma unroll
    for (int it = 0; it < 4; ++it)
        gat[it] = *(const float4*)(atom + (unsigned)nbi[it] * A_FEA + k4);
#pragma unroll
    for (int it = 0; it < 4; ++it) {
        int r = r16 + it * 16;
        uint2 u;
        u.x = pack2bf(gat[it].x, gat[it].y);
        u.y = pack2bf(gat[it].z, gat[it].w);
        *(uint2*)&At[r * LDA + A_FEA + k4] = u;
    }
}

// Per-wave W fragments (B operand) from global into registers, once.
__device__ __forceinline__ void load_wfrag(s16x8 bfr[4][6], const float* __restrict__ W,
                                           const int ct[4], int col, int q8) {
#pragma unroll
    for (int t = 0; t < 4; ++t) {
        const float* wr = W + (ct[t] * 16 + col) * KF;
#pragma unroll
        for (int kc = 0; kc < 6; ++kc) {
            const int kb = kc * 32 + q8;
            s16x8 f;
#pragma unroll
            for (int j = 0; j < 8; ++j) {
                int k = kb + j;
                float v = (k < KF) ? wr[k] : 0.f;
                f[j] = (short)f2bf(v);
            }
            bfr[t][kc] = f;
        }
    }
}

__device__ __forceinline__ void gemm_core(const unsigned short* __restrict__ At,
                                          const s16x8 bfr[4][6],
                                          int r0, int col, int q8, f32x4 acc[2][4]) {
#pragma unroll
    for (int rt = 0; rt < 2; ++rt)
#pragma unroll
        for (int t = 0; t < 4; ++t) acc[rt][t] = (f32x4){0.f, 0.f, 0.f, 0.f};
#pragma unroll
    for (int kc = 0; kc < 6; ++kc) {
        const int k0 = kc * 32;
        const s16x8 a0 = *(const s16x8*)&At[(r0 + col) * LDA + k0 + q8];
        const s16x8 a1 = *(const s16x8*)&At[(r0 + 16 + col) * LDA + k0 + q8];
#pragma unroll
        for (int t = 0; t < 4; ++t) {
            acc[0][t] = __builtin_amdgcn_mfma_f32_16x16x32_bf16(a0, bfr[t][kc], acc[0][t], 0, 0, 0);
            acc[1][t] = __builtin_amdgcn_mfma_f32_16x16x32_bf16(a1, bfr[t][kc], acc[1][t], 0, 0, 0);
        }
    }
}

// ---- pass A: GEMM once; BN1 stats + (optionally) spill gated tile as bf16.
// uint4 layout: gated4[tile64*1024 + (rt*2+half)*256 + tid];
// half0 = filter channels (ct[0],ct[1]), half1 = core channels (ct[2],ct[3]).
// XCD-sliced tile assignment: blockIdx&7 owns a contiguous 1/8 of tiles.
template <bool STORE>
__global__ __launch_bounds__(256, 4)
void k_gemm_spill(const float* __restrict__ atom, const float* __restrict__ nbr,
                  const int* __restrict__ idx, const float* __restrict__ W,
                  float* __restrict__ stats, uint4* __restrict__ gated4) {
    __shared__ __align__(16) unsigned short At[TILE_R * LDA];  // 25600 B
    const int tid = threadIdx.x;
    zero_At_pad(At, tid);

    const int lane = tid & 63;
    const int w    = tid >> 6;
    const int col  = lane & 15;
    const int q8   = (lane >> 4) * 8;
    const int r0   = (w & 1) * 32;
    const int g    = w >> 1;
    const int ct[4] = {2 * g, 2 * g + 1, 2 * g + 4, 2 * g + 5};

    s16x8 bfr[4][6];
    load_wfrag(bfr, W, ct, col, q8);

    float s[4] = {0.f, 0.f, 0.f, 0.f}, q[4] = {0.f, 0.f, 0.f, 0.f};

    // XCD slice: 9375 tiles in 8 slices of 1172 (last 1171)
    const int xcd   = blockIdx.x & 7;
    const int slot  = blockIdx.x >> 3;
    const int nslot = gridDim.x >> 3;
    const int t0 = xcd * 1172;
    const int t1 = min(NTILES, t0 + 1172);

    for (int t = t0 + slot; t < t1; t += nslot) {
        const int rb = t * TILE_R;
        __syncthreads();
        stage_tile(At, atom, nbr, idx, rb, tid);
        __syncthreads();

        f32x4 acc[2][4];
        gemm_core(At, bfr, r0, col, q8, acc);

#pragma unroll
        for (int rt = 0; rt < 2; ++rt)
#pragma unroll
            for (int tt = 0; tt < 4; ++tt)
#pragma unroll
                for (int e = 0; e < 4; ++e) {
                    float v = acc[rt][tt][e];
                    s[tt] += v; q[tt] = fmaf(v, v, q[tt]);
                }
        if (STORE) {
#pragma unroll
            for (int rt = 0; rt < 2; ++rt)
#pragma unroll
                for (int half = 0; half < 2; ++half) {
                    const int tt = half * 2;
                    uint4 u;
                    u.x = pack2bf(acc[rt][tt][0],     acc[rt][tt][1]);
                    u.y = pack2bf(acc[rt][tt][2],     acc[rt][tt][3]);
                    u.z = pack2bf(acc[rt][tt + 1][0], acc[rt][tt + 1][1]);
                    u.w = pack2bf(acc[rt][tt + 1][2], acc[rt][tt + 1][3]);
                    gated4[(size_t)t * 1024 + (rt * 2 + half) * 256 + tid] = u;
                }
        }
    }
#pragma unroll
    for (int tt = 0; tt < 4; ++tt) {
        float sv = s[tt], qv = q[tt];
        sv += __shfl_xor(sv, 16); sv += __shfl_xor(sv, 32);
        qv += __shfl_xor(qv, 16); qv += __shfl_xor(qv, 32);
        if (lane < 16) {
            int c = ct[tt] * 16 + col;
            atomicAdd(&stats[WS_SUM1 + c], sv);
            atomicAdd(&stats[WS_SUMSQ1 + c], qv);
        }
    }
}

// ---- pass B: stream gated bf16; BN1 + sig*softplus; m-sum over 192-row
// (=16 whole atoms) tiles via plain LDS writes + per-thread 12-row sums;
// plain coalesced global stores; BN2 stats accumulated inline. NO atomics
// in the hot path.
__global__ __launch_bounds__(256, 3)
void k_apply(const uint4* __restrict__ gated4,
             const float* __restrict__ g1, const float* __restrict__ b1,
             float* __restrict__ stats, float* __restrict__ dout) {
    __shared__ float S2[192 * S2S];   // 52224 B
    const int tid  = threadIdx.x;
    const int lane = tid & 63;
    const int w    = tid >> 6;
    const int col  = lane & 15;
    const int quad = lane >> 4;
    const int r0   = (w & 1) * 32;
    const int g    = w >> 1;
    const int ct[4] = {2 * g, 2 * g + 1, 2 * g + 4, 2 * g + 5};

    const float invn = 1.f / (float)NROW;
    float sc[4], sh[4];
#pragma unroll
    for (int t = 0; t < 4; ++t) {
        int c = ct[t] * 16 + col;
        float mean = stats[WS_SUM1 + c] * invn;
        float var  = stats[WS_SUMSQ1 + c] * invn - mean * mean;
        sc[t] = g1[c] * rsqrtf(var + BN_EPS);
        sh[t] = b1[c] - mean * sc[t];
    }

    float bs = 0.f, bq = 0.f;

    for (int T = blockIdx.x; T < NT192; T += gridDim.x) {
        __syncthreads();                 // prior reduction reads complete
#pragma unroll
        for (int sub = 0; sub < 3; ++sub) {
            const size_t base = (size_t)(T * 3 + sub) * 1024 + tid;
            uint4 uf0 = gated4[base];          // rt0, filters
            uint4 uc0 = gated4[base + 256];    // rt0, cores
            uint4 uf1 = gated4[base + 512];    // rt1, filters
            uint4 uc1 = gated4[base + 768];    // rt1, cores
            const uint4 UF[2] = {uf0, uf1}, UC[2] = {uc0, uc1};
#pragma unroll
            for (int rt = 0; rt < 2; ++rt) {
#pragma unroll
                for (int p = 0; p < 2; ++p) {
                    unsigned fx = p ? UF[rt].z : UF[rt].x;
                    unsigned fy = p ? UF[rt].w : UF[rt].y;
                    unsigned cx = p ? UC[rt].z : UC[rt].x;
                    unsigned cy = p ? UC[rt].w : UC[rt].y;
                    const float fv[4] = {bf_lo(fx), bf_hi(fx), bf_lo(fy), bf_hi(fy)};
                    const float cv[4] = {bf_lo(cx), bf_hi(cx), bf_lo(cy), bf_hi(cy)};
                    const int c = ct[p] * 16 + col;
#pragma unroll
                    for (int e = 0; e < 4; ++e) {
                        float gF = fmaf(fv[e], sc[p],     sh[p]);
                        float gC = fmaf(cv[e], sc[p + 2], sh[p + 2]);
                        float v  = fsigmoid(gF) * fsoftplus(gC);
                        int row = sub * 64 + r0 + rt * 16 + quad * 4 + e;
                        S2[row * S2S + c] = v;   // unique (row,c) writer
                    }
                }
            }
        }
        __syncthreads();
        // 16 atoms x 64 channels; thread owns 4 (a,c) with c = tid&63 fixed
#pragma unroll
        for (int j = 0; j < 4; ++j) {
            int lin = tid + j * 256;
            int a = lin >> 6, c = lin & 63;
            const float* p = &S2[(a * 12) * S2S + c];
            float sum = 0.f;
#pragma unroll
            for (int m = 0; m < 12; ++m) sum += p[m * S2S];
            dout[((size_t)T * 16 + a) * 64 + c] = sum;
            bs += sum; bq = fmaf(sum, sum, bq);
        }
    }
    // BN2 stats: block-level LDS reduce (c = tid&63), then 128 atomics/block
    __syncthreads();
    S2[tid] = bs; S2[256 + tid] = bq;
    __syncthreads();
    if (tid < 64) {
        float ss = S2[tid] + S2[tid + 64] + S2[tid + 128] + S2[tid + 192];
        float qq = S2[256 + tid] + S2[256 + tid + 64] + S2[256 + tid + 128] + S2[256 + tid + 192];
        atomicAdd(&stats[WS_SUM2 + tid], ss);
        atomicAdd(&stats[WS_SUMSQ2 + tid], qq);
    }
}

// ---- fallback two-pass main kernel (ws too small): GEMM + atomic epilogue.
__global__ __launch_bounds__(256, 4)
void k_gemm_main(const float* __restrict__ atom, const float* __restrict__ nbr,
                 const int* __restrict__ idx, const float* __restrict__ W,
                 const float* __restrict__ g1, const float* __restrict__ b1,
                 const float* __restrict__ stats, float* __restrict__ dout) {
    __shared__ __align__(16) unsigned short At[TILE_R * LDA];
    __shared__ float S[7 * 64];
    const int tid = threadIdx.x;
    zero_At_pad(At, tid);
    for (int i = tid; i < 7 * 64; i += 256) S[i] = 0.f;

    const int lane = tid & 63;
    const int w    = tid >> 6;
    const int col  = lane & 15;
    const int q8   = (lane >> 4) * 8;
    const int r0   = (w & 1) * 32;
    const int g    = w >> 1;
    const int ct[4] = {2 * g, 2 * g + 1, 2 * g + 4, 2 * g + 5};

    s16x8 bfr[4][6];
    load_wfrag(bfr, W, ct, col, q8);

    const float invn = 1.f / (float)NROW;
    float sc[4], sh[4];
#pragma unroll
    for (int t = 0; t < 4; ++t) {
        int c = ct[t] * 16 + col;
        float mean = stats[WS_SUM1 + c] * invn;
        float var  = stats[WS_SUMSQ1 + c] * invn - mean * mean;
        sc[t] = g1[c] * rsqrtf(var + BN_EPS);
        sh[t] = b1[c] - mean * sc[t];
    }

    const int step = gridDim.x * TILE_R;
    for (int rb = blockIdx.x * TILE_R; rb < NROW; rb += step) {
        __syncthreads();
        stage_tile(At, atom, nbr, idx, rb, tid);
        __syncthreads();

        f32x4 acc[2][4];
        gemm_core(At, bfr, r0, col, q8, acc);

        const int a0i = rb / M_NBR;
#pragma unroll
        for (int p = 0; p < 2; ++p) {
            const int c = ct[p] * 16 + col;
#pragma unroll
            for (int rt = 0; rt < 2; ++rt)
#pragma unroll
                for (int e = 0; e < 4; ++e) {
                    float gF = fmaf(acc[rt][p][e],     sc[p],     sh[p]);
                    float gC = fmaf(acc[rt][p + 2][e], sc[p + 2], sh[p + 2]);
                    float v  = fsigmoid(gF) * fsoftplus(gC);
                    int row_local = r0 + rt * 16 + (lane >> 4) * 4 + e;
                    int al = (rb + row_local) / M_NBR - a0i;
                    atomicAdd(&S[al * 64 + c], v);
                }
        }
        __syncthreads();
        const int amax = (rb + TILE_R - 1) / M_NBR - a0i;
        for (int i = tid; i < 7 * 64; i += 256) {
            float v = S[i];
            S[i] = 0.f;
            int a = i >> 6;
            if (a <= amax) atomicAdd(&dout[(a0i + a) * 64 + (i & 63)], v);
        }
    }
}

__global__ __launch_bounds__(256, 1)
void k_bn2_stats(const float* __restrict__ dout, float* __restrict__ stats) {
    int tid = threadIdx.x;
    int c = tid & 63;
    int g = tid >> 6;
    float s = 0.f, q = 0.f;
    for (int n = blockIdx.x * 4 + g; n < N_ATOMS; n += gridDim.x * 4) {
        float v = dout[n * 64 + c];
        s += v; q = fmaf(v, v, q);
    }
    __shared__ float red[4][64];
    red[g][c] = s;
    __syncthreads();
    if (g == 0)
        atomicAdd(&stats[WS_SUM2 + c], red[0][c] + red[1][c] + red[2][c] + red[3][c]);
    __syncthreads();
    red[g][c] = q;
    __syncthreads();
    if (g == 0)
        atomicAdd(&stats[WS_SUMSQ2 + c], red[0][c] + red[1][c] + red[2][c] + red[3][c]);
}

__global__ void k_final(const float* __restrict__ atom, const float* __restrict__ g2,
                        const float* __restrict__ b2, const float* __restrict__ stats,
                        float* __restrict__ dout) {
    int i0 = blockIdx.x * blockDim.x + threadIdx.x;
    int c = i0 & 63;
    const float invn = 1.f / (float)N_ATOMS;
    float mean = stats[WS_SUM2 + c] * invn;
    float var  = stats[WS_SUMSQ2 + c] * invn - mean * mean;
    float sc   = g2[c] * rsqrtf(var + BN_EPS);
    float sh   = b2[c] - mean * sc;
    int stride = gridDim.x * blockDim.x;
    for (int i = i0; i < N_ATOMS * A_FEA; i += stride) {
        float v = fmaf(dout[i], sc, sh) + atom[i];
        dout[i] = fsoftplus(v);
    }
}

extern "C" void kernel_launch(void* const* d_in, const int* in_sizes, int n_in,
                              void* d_out, int out_size, void* d_ws, size_t ws_size,
                              hipStream_t stream) {
    const float* atom = (const float*)d_in[0];
    const float* nbr  = (const float*)d_in[1];
    const int*   idx  = (const int*)d_in[2];
    const float* W    = (const float*)d_in[3];
    // d_in[4] (bias b) is mathematically absorbed by BN1 -> unused
    const float* g1   = (const float*)d_in[5];
    const float* b1   = (const float*)d_in[6];
    const float* g2   = (const float*)d_in[7];
    const float* b2   = (const float*)d_in[8];
    float* dout  = (float*)d_out;
    float* stats = (float*)d_ws;
    uint4* gated4 = (uint4*)((char*)d_ws + WS_GATED_OFF);

    const bool fused = ws_size >= (WS_GATED_OFF + GATED_BYTES);

    if (fused) {
        k_zero_stats<<<2, 256, 0, stream>>>(stats);
        k_gemm_spill<true><<<1536, 256, 0, stream>>>(atom, nbr, idx, W, stats, gated4);
        k_apply<<<768, 256, 0, stream>>>(gated4, g1, b1, stats, dout);
        k_final<<<512, 256, 0, stream>>>(atom, g2, b2, stats, dout);
    } else {
        k_zero<<<512, 256, 0, stream>>>(dout, stats);
        k_gemm_spill<false><<<1536, 256, 0, stream>>>(atom, nbr, idx, W, stats, nullptr);
        k_gemm_main<<<1024, 256, 0, stream>>>(atom, nbr, idx, W, g1, b1, stats, dout);
        k_bn2_stats<<<256, 256, 0, stream>>>(dout, stats);
        k_final<<<512, 256, 0, stream>>>(atom, g2, b2, stats, dout);
    }
}

// Round 7
// 269.899 us; speedup vs baseline: 2.3097x; 1.7544x over previous
//
#include <hip/hip_runtime.h>
#include <math.h>

#define N_ATOMS 50000
#define M_NBR   12
#define A_FEA   64
#define B_FEA   41
#define KF      169      // 2*A + B
#define KP      192      // padded K (6 chunks of 32)
#define LDA     200      // LDS row stride in bf16 (400 B -> free 2-way banking)
#define OC      128      // 2*A
#define NROW    600000   // N_ATOMS * M_NBR
#define TR32    32       // rows per GEMM tile
#define NT32    18750    // NROW / 32
#define NT192   3125     // NROW / 192 (16-atom apply tiles)
#define S2S     68       // apply scratch stride (floats)
#define BN_EPS  1e-5f
#define L2E     1.44269504088896340736f
#define LN2     0.693147180559945309417f

// d_ws layout
#define WS_SUM1   0
#define WS_SUMSQ1 128
#define WS_SUM2   256
#define WS_SUMSQ2 320
#define WS_NFLOAT 384
#define WS_GATED_OFF 2048ull
#define GATED_BYTES  ((size_t)NT32 * 1024 * 8)   // 153.6 MB of bf16

typedef __attribute__((ext_vector_type(8))) short s16x8;
typedef __attribute__((ext_vector_type(4))) float f32x4;

__device__ __forceinline__ float fsigmoid(float x) {
    float e = __builtin_amdgcn_exp2f(-x * L2E);
    return __builtin_amdgcn_rcpf(1.f + e);
}
__device__ __forceinline__ float fsoftplus(float x) {
    float e = __builtin_amdgcn_exp2f(-fabsf(x) * L2E);
    return fmaxf(x, 0.f) + __builtin_amdgcn_logf(1.f + e) * LN2;
}
__device__ __forceinline__ unsigned short f2bf(float f) {
    unsigned int u = __float_as_uint(f);
    u += 0x7FFFu + ((u >> 16) & 1u);     // RNE
    return (unsigned short)(u >> 16);
}
__device__ __forceinline__ unsigned int pack2bf(float lo, float hi) {
    return (unsigned int)f2bf(lo) | ((unsigned int)f2bf(hi) << 16);
}
__device__ __forceinline__ float bf_lo(unsigned int u) { return __uint_as_float(u << 16); }
__device__ __forceinline__ float bf_hi(unsigned int u) { return __uint_as_float(u & 0xFFFF0000u); }

__global__ void k_zero_stats(float* __restrict__ stats) {
    int i = blockIdx.x * blockDim.x + threadIdx.x;
    if (i < WS_NFLOAT) stats[i] = 0.f;
}
__global__ void k_zero(float* __restrict__ dout, float* __restrict__ stats) {
    int i = blockIdx.x * blockDim.x + threadIdx.x;
    int stride = gridDim.x * blockDim.x;
    for (int j = i; j < N_ATOMS * A_FEA; j += stride) dout[j] = 0.f;
    if (i < WS_NFLOAT) stats[i] = 0.f;
}

// ---- register staging state for one 32-row tile ----------------------------
struct TileRegs {
    float4 selfv[2];
    float4 gat[2];
    float4 bond0, bond1;
};

__device__ __forceinline__ void issue_selfbond(TileRegs& R, const float* __restrict__ atom,
                                               const float* __restrict__ nbr,
                                               int rb, int r16, int k4, int tid) {
#pragma unroll
    for (int it = 0; it < 2; ++it) {
        int row = rb + r16 + it * 16;
        R.selfv[it] = *(const float4*)(atom + ((unsigned)row / 12u) * A_FEA + k4);
    }
    const float* bb = nbr + (size_t)rb * B_FEA;   // 1312 floats = 328 float4, 16B-aligned
    R.bond0 = *(const float4*)(bb + (size_t)tid * 4);
    if (tid < 72) R.bond1 = *(const float4*)(bb + (size_t)(256 + tid) * 4);
}
__device__ __forceinline__ void issue_gat(TileRegs& R, const float* __restrict__ atom,
                                          const int nbi[2], int k4) {
#pragma unroll
    for (int it = 0; it < 2; ++it)
        R.gat[it] = *(const float4*)(atom + (unsigned)nbi[it] * A_FEA + k4);
}
__device__ __forceinline__ void write_tile(unsigned short* __restrict__ At,
                                           const TileRegs& R, int r16, int k4, int tid) {
#pragma unroll
    for (int it = 0; it < 2; ++it) {
        int r = r16 + it * 16;
        uint2 u;
        u.x = pack2bf(R.selfv[it].x, R.selfv[it].y);
        u.y = pack2bf(R.selfv[it].z, R.selfv[it].w);
        *(uint2*)&At[r * LDA + k4] = u;
        uint2 v;
        v.x = pack2bf(R.gat[it].x, R.gat[it].y);
        v.y = pack2bf(R.gat[it].z, R.gat[it].w);
        *(uint2*)&At[r * LDA + A_FEA + k4] = v;
    }
    {
        const float bv[4] = {R.bond0.x, R.bond0.y, R.bond0.z, R.bond0.w};
#pragma unroll
        for (int e = 0; e < 4; ++e) {
            int le = tid * 4 + e;                    // < 1024
            unsigned r = (unsigned)le / 41u, j = (unsigned)le - r * 41u;
            At[r * LDA + 2 * A_FEA + j] = f2bf(bv[e]);
        }
    }
    if (tid < 72) {
        const float bv[4] = {R.bond1.x, R.bond1.y, R.bond1.z, R.bond1.w};
#pragma unroll
        for (int e = 0; e < 4; ++e) {
            int le = 1024 + tid * 4 + e;             // < 1312
            unsigned r = (unsigned)le / 41u, j = (unsigned)le - r * 41u;
            At[r * LDA + 2 * A_FEA + j] = f2bf(bv[e]);
        }
    }
}

// ---- pass A: double-buffered MFMA GEMM; BN1 stats (+ optional bf16 spill).
// Tile = 32 rows x 128 ch; wave w owns ct tiles {w, w+4} (filter/core pair
// share lanes). Spill layout (uint2): gated[t*1024 + (rt*2+tt)*256 + tid].
template <bool STORE>
__global__ __launch_bounds__(256, 3)
void k_gemm_spill(const float* __restrict__ atom, const float* __restrict__ nbr,
                  const int* __restrict__ idx, const float* __restrict__ W,
                  float* __restrict__ stats, uint2* __restrict__ gated) {
    __shared__ __align__(16) unsigned short At[2][TR32 * LDA];   // 2 x 12800 B
    const int tid = threadIdx.x;
    for (int i = tid; i < 2 * TR32 * (KP - KF); i += 256) {      // zero K-pad
        int b  = i / (TR32 * (KP - KF));
        int ii = i - b * (TR32 * (KP - KF));
        int r  = ii / (KP - KF);
        int j  = KF + ii - r * (KP - KF);
        At[b][r * LDA + j] = 0;
    }
    const int lane = tid & 63, gg = tid >> 6;
    const int col  = lane & 15, q8 = (lane >> 4) * 8;
    const int r16  = tid >> 4;          // 0..15
    const int k4   = (tid & 15) * 4;

    s16x8 bfr[2][6];                    // 48 VGPRs of W fragments
#pragma unroll
    for (int tt = 0; tt < 2; ++tt) {
        const float* wr = W + ((gg + tt * 4) * 16 + col) * KF;
#pragma unroll
        for (int kc = 0; kc < 6; ++kc) {
            int kb = kc * 32 + q8;
            s16x8 f;
#pragma unroll
            for (int j = 0; j < 8; ++j) {
                int k = kb + j;
                f[j] = (short)f2bf(k < KF ? wr[k] : 0.f);
            }
            bfr[tt][kc] = f;
        }
    }

    const int per = (NT32 + gridDim.x - 1) / gridDim.x;   // contiguous chunks
    const int tA = blockIdx.x * per;
    const int tB = min(NT32, tA + per);

    float s[2] = {0.f, 0.f}, q[2] = {0.f, 0.f};
    TileRegs R;
    int nbiN[2];
    if (tA < tB) {
        int rb = tA * TR32;
        int nbiC[2] = {idx[rb + r16], idx[rb + r16 + 16]};
        issue_selfbond(R, atom, nbr, rb, r16, k4, tid);
        issue_gat(R, atom, nbiC, k4);
        if (tA + 1 < tB) {
            int rb1 = rb + TR32;
            nbiN[0] = idx[rb1 + r16]; nbiN[1] = idx[rb1 + r16 + 16];
        }
    }
    int p = 0;
    for (int t = tA; t < tB; ++t) {
        write_tile(At[p], R, r16, k4, tid);       // waits on tile-t loads (1 tile in flight)
        if (t + 1 < tB) {                         // issue tile t+1 loads now
            issue_selfbond(R, atom, nbr, (t + 1) * TR32, r16, k4, tid);
            issue_gat(R, atom, nbiN, k4);         // idx prefetched 1 tile earlier
            if (t + 2 < tB) {
                int rb2 = (t + 2) * TR32;
                nbiN[0] = idx[rb2 + r16]; nbiN[1] = idx[rb2 + r16 + 16];
            }
        }
        __syncthreads();                          // buf[p] staged by all waves
        const unsigned short* A = At[p];
        f32x4 acc[2][2];
#pragma unroll
        for (int rt = 0; rt < 2; ++rt)
#pragma unroll
            for (int tt = 0; tt < 2; ++tt) acc[rt][tt] = (f32x4){0.f, 0.f, 0.f, 0.f};
#pragma unroll
        for (int kc = 0; kc < 6; ++kc) {
            const int k0 = kc * 32;
            const s16x8 a0 = *(const s16x8*)&A[(col) * LDA + k0 + q8];
            const s16x8 a1 = *(const s16x8*)&A[(16 + col) * LDA + k0 + q8];
#pragma unroll
            for (int tt = 0; tt < 2; ++tt) {
                acc[0][tt] = __builtin_amdgcn_mfma_f32_16x16x32_bf16(a0, bfr[tt][kc], acc[0][tt], 0, 0, 0);
                acc[1][tt] = __builtin_amdgcn_mfma_f32_16x16x32_bf16(a1, bfr[tt][kc], acc[1][tt], 0, 0, 0);
            }
        }
#pragma unroll
        for (int tt = 0; tt < 2; ++tt)
#pragma unroll
            for (int rt = 0; rt < 2; ++rt)
#pragma unroll
                for (int e = 0; e < 4; ++e) {
                    float v = acc[rt][tt][e];
                    s[tt] += v; q[tt] = fmaf(v, v, q[tt]);
                }
        if (STORE) {
#pragma unroll
            for (int rt = 0; rt < 2; ++rt)
#pragma unroll
                for (int tt = 0; tt < 2; ++tt) {
                    uint2 u;
                    u.x = pack2bf(acc[rt][tt][0], acc[rt][tt][1]);
                    u.y = pack2bf(acc[rt][tt][2], acc[rt][tt][3]);
                    gated[(size_t)t * 1024 + (rt * 2 + tt) * 256 + tid] = u;
                }
        }
        p ^= 1;
        // single barrier/iter is safe: re-writing buf[p] at iter t+2 requires
        // passing barrier(t+1); reaching barrier(t+1) implies the wave's buf[p]
        // reads from iter t completed (lgkmcnt drained before s_barrier).
    }
#pragma unroll
    for (int tt = 0; tt < 2; ++tt) {
        float sv = s[tt], qv = q[tt];
        sv += __shfl_xor(sv, 16); sv += __shfl_xor(sv, 32);
        qv += __shfl_xor(qv, 16); qv += __shfl_xor(qv, 32);
        if (lane < 16) {
            int c = (gg + tt * 4) * 16 + col;
            atomicAdd(&stats[WS_SUM1 + c], sv);
            atomicAdd(&stats[WS_SUMSQ1 + c], qv);
        }
    }
}

// ---- pass B: stream gated bf16; BN1 + sigmoid*softplus; m-sum over 192-row
// (16-atom) tiles via plain LDS + per-thread 12-row sums; BN2 stats inline.
__global__ __launch_bounds__(256, 3)
void k_apply(const uint2* __restrict__ gated,
             const float* __restrict__ g1, const float* __restrict__ b1,
             float* __restrict__ stats, float* __restrict__ dout) {
    __shared__ float S2[192 * S2S];   // 52224 B
    const int tid = threadIdx.x, lane = tid & 63;
    const int col = lane & 15, quad = lane >> 4, gg = tid >> 6;
    const int cF = gg * 16 + col, cC = cF + 64;

    const float invn = 1.f / (float)NROW;
    float meanF = stats[WS_SUM1 + cF] * invn;
    float varF  = stats[WS_SUMSQ1 + cF] * invn - meanF * meanF;
    float scF   = g1[cF] * rsqrtf(varF + BN_EPS), shF = b1[cF] - meanF * scF;
    float meanC = stats[WS_SUM1 + cC] * invn;
    float varC  = stats[WS_SUMSQ1 + cC] * invn - meanC * meanC;
    float scC   = g1[cC] * rsqrtf(varC + BN_EPS), shC = b1[cC] - meanC * scC;

    float bs = 0.f, bq = 0.f;
    for (int T = blockIdx.x; T < NT192; T += gridDim.x) {
        __syncthreads();               // previous reduction reads done
        uint2 F[6][2], C[6][2];        // batch all 24 loads, then process
#pragma unroll
        for (int sub = 0; sub < 6; ++sub) {
            const size_t base = (size_t)(T * 6 + sub) * 1024 + tid;
#pragma unroll
            for (int rt = 0; rt < 2; ++rt) {
                F[sub][rt] = gated[base + (rt * 2) * 256];
                C[sub][rt] = gated[base + (rt * 2 + 1) * 256];
            }
        }
#pragma unroll
        for (int sub = 0; sub < 6; ++sub)
#pragma unroll
            for (int rt = 0; rt < 2; ++rt) {
                const uint2 uf = F[sub][rt], uc = C[sub][rt];
                const float fv[4] = {bf_lo(uf.x), bf_hi(uf.x), bf_lo(uf.y), bf_hi(uf.y)};
                const float cv[4] = {bf_lo(uc.x), bf_hi(uc.x), bf_lo(uc.y), bf_hi(uc.y)};
#pragma unroll
                for (int e = 0; e < 4; ++e) {
                    float gF = fmaf(fv[e], scF, shF);
                    float gC = fmaf(cv[e], scC, shC);
                    float v  = fsigmoid(gF) * fsoftplus(gC);
                    int row = sub * 32 + rt * 16 + quad * 4 + e;
                    S2[row * S2S + cF] = v;    // unique (row, c) writer
                }
            }
        __syncthreads();
#pragma unroll
        for (int j = 0; j < 4; ++j) {
            int lin = tid + j * 256;
            int a = lin >> 6, c = lin & 63;
            const float* pp = &S2[(a * 12) * S2S + c];
            float sum = 0.f;
#pragma unroll
            for (int m = 0; m < 12; ++m) sum += pp[m * S2S];
            dout[((size_t)T * 16 + a) * 64 + c] = sum;
            bs += sum; bq = fmaf(sum, sum, bq);
        }
    }
    __syncthreads();
    S2[tid] = bs; S2[256 + tid] = bq;
    __syncthreads();
    if (tid < 64) {
        float ss = S2[tid] + S2[tid + 64] + S2[tid + 128] + S2[tid + 192];
        float qq = S2[256 + tid] + S2[256 + tid + 64] + S2[256 + tid + 128] + S2[256 + tid + 192];
        atomicAdd(&stats[WS_SUM2 + tid], ss);
        atomicAdd(&stats[WS_SUMSQ2 + tid], qq);
    }
}

// ---- fallback main (ws too small): same GEMM structure, atomic epilogue.
__global__ __launch_bounds__(256, 2)
void k_gemm_main(const float* __restrict__ atom, const float* __restrict__ nbr,
                 const int* __restrict__ idx, const float* __restrict__ W,
                 const float* __restrict__ g1, const float* __restrict__ b1,
                 const float* __restrict__ stats, float* __restrict__ dout) {
    __shared__ __align__(16) unsigned short At[TR32 * LDA];
    __shared__ float S[4 * 64];       // <=4 atoms per 32-row tile
    const int tid = threadIdx.x;
    for (int i = tid; i < TR32 * (KP - KF); i += 256) {
        int r = i / (KP - KF), j = KF + i - r * (KP - KF);
        At[r * LDA + j] = 0;
    }
    for (int i = tid; i < 4 * 64; i += 256) S[i] = 0.f;
    const int lane = tid & 63, gg = tid >> 6;
    const int col = lane & 15, q8 = (lane >> 4) * 8, quad = lane >> 4;
    const int r16 = tid >> 4, k4 = (tid & 15) * 4;

    s16x8 bfr[2][6];
#pragma unroll
    for (int tt = 0; tt < 2; ++tt) {
        const float* wr = W + ((gg + tt * 4) * 16 + col) * KF;
#pragma unroll
        for (int kc = 0; kc < 6; ++kc) {
            int kb = kc * 32 + q8;
            s16x8 f;
#pragma unroll
            for (int j = 0; j < 8; ++j) { int k = kb + j; f[j] = (short)f2bf(k < KF ? wr[k] : 0.f); }
            bfr[tt][kc] = f;
        }
    }
    const float invn = 1.f / (float)NROW;
    float sc[2], sh[2];
#pragma unroll
    for (int tt = 0; tt < 2; ++tt) {
        int c = (gg + tt * 4) * 16 + col;
        float mean = stats[WS_SUM1 + c] * invn;
        float var  = stats[WS_SUMSQ1 + c] * invn - mean * mean;
        sc[tt] = g1[c] * rsqrtf(var + BN_EPS);
        sh[tt] = b1[c] - mean * sc[tt];
    }
    const int per = (NT32 + gridDim.x - 1) / gridDim.x;
    const int tA = blockIdx.x * per, tB = min(NT32, tA + per);
    for (int t = tA; t < tB; ++t) {
        const int rb = t * TR32;
        __syncthreads();
        {
            TileRegs R;
            int nbiC[2] = {idx[rb + r16], idx[rb + r16 + 16]};
            issue_selfbond(R, atom, nbr, rb, r16, k4, tid);
            issue_gat(R, atom, nbiC, k4);
            write_tile(At, R, r16, k4, tid);
        }
        __syncthreads();
        f32x4 acc[2][2];
#pragma unroll
        for (int rt = 0; rt < 2; ++rt)
#pragma unroll
            for (int tt = 0; tt < 2; ++tt) acc[rt][tt] = (f32x4){0.f, 0.f, 0.f, 0.f};
#pragma unroll
        for (int kc = 0; kc < 6; ++kc) {
            const int k0 = kc * 32;
            const s16x8 a0 = *(const s16x8*)&At[(col) * LDA + k0 + q8];
            const s16x8 a1 = *(const s16x8*)&At[(16 + col) * LDA + k0 + q8];
#pragma unroll
            for (int tt = 0; tt < 2; ++tt) {
                acc[0][tt] = __builtin_amdgcn_mfma_f32_16x16x32_bf16(a0, bfr[tt][kc], acc[0][tt], 0, 0, 0);
                acc[1][tt] = __builtin_amdgcn_mfma_f32_16x16x32_bf16(a1, bfr[tt][kc], acc[1][tt], 0, 0, 0);
            }
        }
        const int a0i = rb / M_NBR;
#pragma unroll
        for (int rt = 0; rt < 2; ++rt)
#pragma unroll
            for (int e = 0; e < 4; ++e) {
                float gF = fmaf(acc[rt][0][e], sc[0], sh[0]);
                float gC = fmaf(acc[rt][1][e], sc[1], sh[1]);
                float v  = fsigmoid(gF) * fsoftplus(gC);
                int row = rb + rt * 16 + quad * 4 + e;
                atomicAdd(&S[(row / M_NBR - a0i) * 64 + gg * 16 + col], v);
            }
        __syncthreads();
        const int amax = (rb + TR32 - 1) / M_NBR - a0i;
        for (int i = tid; i < 4 * 64; i += 256) {
            float v = S[i];
            S[i] = 0.f;
            int a = i >> 6;
            if (a <= amax) atomicAdd(&dout[(a0i + a) * 64 + (i & 63)], v);
        }
    }
}

__global__ __launch_bounds__(256, 1)
void k_bn2_stats(const float* __restrict__ dout, float* __restrict__ stats) {
    int tid = threadIdx.x;
    int c = tid & 63;
    int g = tid >> 6;
    float s = 0.f, q = 0.f;
    for (int n = blockIdx.x * 4 + g; n < N_ATOMS; n += gridDim.x * 4) {
        float v = dout[n * 64 + c];
        s += v; q = fmaf(v, v, q);
    }
    __shared__ float red[4][64];
    red[g][c] = s;
    __syncthreads();
    if (g == 0)
        atomicAdd(&stats[WS_SUM2 + c], red[0][c] + red[1][c] + red[2][c] + red[3][c]);
    __syncthreads();
    red[g][c] = q;
    __syncthreads();
    if (g == 0)
        atomicAdd(&stats[WS_SUMSQ2 + c], red[0][c] + red[1][c] + red[2][c] + red[3][c]);
}

__global__ void k_final(const float* __restrict__ atom, const float* __restrict__ g2,
                        const float* __restrict__ b2, const float* __restrict__ stats,
                        float* __restrict__ dout) {
    int i0 = blockIdx.x * blockDim.x + threadIdx.x;
    int c = i0 & 63;
    const float invn = 1.f / (float)N_ATOMS;
    float mean = stats[WS_SUM2 + c] * invn;
    float var  = stats[WS_SUMSQ2 + c] * invn - mean * mean;
    float sc   = g2[c] * rsqrtf(var + BN_EPS);
    float sh   = b2[c] - mean * sc;
    int stride = gridDim.x * blockDim.x;
    for (int i = i0; i < N_ATOMS * A_FEA; i += stride) {
        float v = fmaf(dout[i], sc, sh) + atom[i];
        dout[i] = fsoftplus(v);
    }
}

extern "C" void kernel_launch(void* const* d_in, const int* in_sizes, int n_in,
                              void* d_out, int out_size, void* d_ws, size_t ws_size,
                              hipStream_t stream) {
    const float* atom = (const float*)d_in[0];
    const float* nbr  = (const float*)d_in[1];
    const int*   idx  = (const int*)d_in[2];
    const float* W    = (const float*)d_in[3];
    // d_in[4] (bias b) is mathematically absorbed by BN1 -> unused
    const float* g1   = (const float*)d_in[5];
    const float* b1   = (const float*)d_in[6];
    const float* g2   = (const float*)d_in[7];
    const float* b2   = (const float*)d_in[8];
    float* dout  = (float*)d_out;
    float* stats = (float*)d_ws;
    uint2* gated = (uint2*)((char*)d_ws + WS_GATED_OFF);

    const bool fused = ws_size >= (WS_GATED_OFF + GATED_BYTES);

    if (fused) {
        k_zero_stats<<<2, 256, 0, stream>>>(stats);
        k_gemm_spill<true><<<1024, 256, 0, stream>>>(atom, nbr, idx, W, stats, gated);
        k_apply<<<768, 256, 0, stream>>>(gated, g1, b1, stats, dout);
        k_final<<<512, 256, 0, stream>>>(atom, g2, b2, stats, dout);
    } else {
        k_zero<<<512, 256, 0, stream>>>(dout, stats);
        k_gemm_spill<false><<<1024, 256, 0, stream>>>(atom, nbr, idx, W, stats, nullptr);
        k_gemm_main<<<1024, 256, 0, stream>>>(atom, nbr, idx, W, g1, b1, stats, dout);
        k_bn2_stats<<<256, 256, 0, stream>>>(dout, stats);
        k_final<<<512, 256, 0, stream>>>(atom, g2, b2, stats, dout);
    }
}